// Round 9
// baseline (523.166 us; speedup 1.0000x reference)
//
#include <hip/hip_runtime.h>
#include <hip/hip_bf16.h>
#include <stdint.h>

// Problem constants (from setup_inputs)
#define T_DIM 2048
#define N_DIM 16
#define I_DIM 1024
#define H_DIM 2048
#define O_DIM 1024
#define K_TAPS 12
#define MROWS (N_DIM * T_DIM)   // 32768 rows of (n,t)
#define BN_EPS 1e-5f

// conv decomposition: subsample space per parity, length 1024
#define S_LEN 1024
#define TCHUNK 48
#define SCHUNKS 22              // ceil(1024/48)
#define NPART (SCHUNKS * 2 * N_DIM)   // 704 partial-sum slots per half

typedef __attribute__((ext_vector_type(8))) short bf16x8;
typedef __attribute__((ext_vector_type(4))) float f32x4;

__device__ __forceinline__ unsigned short f2bf_rne(float f) {
    union { float f; unsigned u; } v; v.f = f;
    unsigned u = v.u;
    unsigned r = u + 0x7fffu + ((u >> 16) & 1u);
    return (unsigned short)(r >> 16);
}

__device__ __forceinline__ float bf2f(unsigned short x) {
    union { unsigned u; float f; } v; v.u = ((unsigned)x) << 16; return v.f;
}

// ---------------- fp32 -> bf16 conversion (vectorized x4) ----------------
__global__ void cvt_kernel(const float* __restrict__ in, unsigned short* __restrict__ out, int n4) {
    int i = blockIdx.x * blockDim.x + threadIdx.x;
    int stride = gridDim.x * blockDim.x;
    for (; i < n4; i += stride) {
        float4 v = ((const float4*)in)[i];
        ushort4 o;
        o.x = f2bf_rne(v.x); o.y = f2bf_rne(v.y);
        o.z = f2bf_rne(v.z); o.w = f2bf_rne(v.w);
        ((ushort4*)out)[i] = o;
    }
}

__device__ __forceinline__ void gload_lds16(const void* g, void* l) {
    __builtin_amdgcn_global_load_lds(
        (const __attribute__((address_space(1))) unsigned int*)g,
        (__attribute__((address_space(3))) unsigned int*)l, 16, 0, 0);
}

// ---------------- 256x256 8-phase bf16 MFMA GEMM, C = A * B^T ----------------
// (R4-verified version: gload_lds both paths, counted vmcnt(2) at phases 0/4.)
template<int PERM, int EPI, int KD, int NCOLS>
__global__ __launch_bounds__(512, 2) void gemm256(
    const unsigned short* __restrict__ A,
    const unsigned short* __restrict__ B,
    void* __restrict__ Cout,
    const float* __restrict__ bias)
{
    __shared__ char lds[131072];   // buf b: A at b*65536, B at b*65536+32768

    const int tid  = threadIdx.x;
    const int wid  = tid >> 6;
    const int lane = tid & 63;
    const int wr   = (wid >> 2) * 128;    // wave row offset (2 warps_m)
    const int wc   = (wid & 3) * 64;      // wave col offset (4 warps_n)
    const int fr   = lane & 15;
    const int fh   = lane >> 4;           // 0..3

    // XCD-aware bijective swizzle (nwg % 8 == 0 for both launches)
    const int nwg = gridDim.x;
    const int lin = blockIdx.x;
    const int tile = (lin & 7) * (nwg >> 3) + (lin >> 3);
    const int ntx = NCOLS / 256;
    const long c0 = (long)(tile % ntx) * 256;
    const long r0 = (long)(tile / ntx) * 256;

    long aBase, aStride;
    if (PERM) {
        const long n0 = r0 / T_DIM;
        const long t0 = r0 % T_DIM;       // 256-row tile stays within one n
        aBase = (t0 * N_DIM + n0) * (long)KD;
        aStride = (long)N_DIM * KD;
    } else {
        aBase = r0 * (long)KD;
        aStride = KD;
    }
    const long bBase = c0 * (long)KD;

    auto stage_half = [&](int buf, int mat, int h, int kt) {
        char* mbase = lds + buf * 65536 + mat * 32768 + h * 16384;
#pragma unroll
        for (int j = 0; j < 2; ++j) {
            const int row = h * 128 + j * 64 + (tid >> 3);
            const int g   = (tid & 7) ^ (row & 7);      // inverse swizzle on source
            long gelem;
            if (mat == 0) gelem = aBase + (long)row * aStride + (long)kt * 64 + g * 8;
            else          gelem = bBase + (long)row * (long)KD + (long)kt * 64 + g * 8;
            gload_lds16((const char*)(mat == 0 ? A : B) + gelem * 2,
                        mbase + j * 8192 + tid * 16);
        }
    };

    auto rdA = [&](int buf, int m, int ks) -> bf16x8 {
        const int row = wr + m * 16 + fr;
        const int blk = ks * 4 + fh;
        return *(const bf16x8*)(lds + buf * 65536 + row * 128 + ((blk ^ (row & 7)) << 4));
    };
    auto rdB = [&](int buf, int n, int ks) -> bf16x8 {
        const int row = wc + n * 16 + fr;
        const int blk = ks * 4 + fh;
        return *(const bf16x8*)(lds + buf * 65536 + 32768 + row * 128 + ((blk ^ (row & 7)) << 4));
    };

    f32x4 acc[8][4] = {};

    // prologue: stage tile 0 into buf0 (8 loads/thread)
    stage_half(0, 0, 0, 0); stage_half(0, 0, 1, 0);
    stage_half(0, 1, 0, 0); stage_half(0, 1, 1, 0);

    const int KT  = KD / 64;
    const int KT2 = KT / 2;
    for (int i = 0; i < KT2; ++i) {
        const int tB = 2 * i + 1;
        const bool haveNext = (i + 1 < KT2);
        bf16x8 bfr[4][2];

        // ---- phases 0-3: compute tile 2i from buf0; stage tile 2i+1 into buf1
#pragma unroll
        for (int q = 0; q < 4; ++q) {
            stage_half(1, q >> 1, q & 1, tB);
            bf16x8 af[2][2];
            if (q == 0) {
                asm volatile("s_waitcnt vmcnt(2)" ::: "memory");
                __builtin_amdgcn_s_barrier();
#pragma unroll
                for (int n = 0; n < 4; ++n)
#pragma unroll
                    for (int ks = 0; ks < 2; ++ks) bfr[n][ks] = rdB(0, n, ks);
#pragma unroll
                for (int mm = 0; mm < 2; ++mm)
#pragma unroll
                    for (int ks = 0; ks < 2; ++ks) af[mm][ks] = rdA(0, q * 2 + mm, ks);
            } else {
#pragma unroll
                for (int mm = 0; mm < 2; ++mm)
#pragma unroll
                    for (int ks = 0; ks < 2; ++ks) af[mm][ks] = rdA(0, q * 2 + mm, ks);
                __builtin_amdgcn_s_barrier();
            }
            __builtin_amdgcn_s_setprio(1);
#pragma unroll
            for (int mm = 0; mm < 2; ++mm)
#pragma unroll
                for (int n = 0; n < 4; ++n)
#pragma unroll
                    for (int ks = 0; ks < 2; ++ks)
                        acc[q * 2 + mm][n] = __builtin_amdgcn_mfma_f32_16x16x32_bf16(
                            af[mm][ks], bfr[n][ks], acc[q * 2 + mm][n], 0, 0, 0);
            __builtin_amdgcn_s_setprio(0);
            __builtin_amdgcn_s_barrier();
        }

        // ---- phases 4-7: compute tile 2i+1 from buf1; stage tile 2i+2 into buf0
#pragma unroll
        for (int q = 0; q < 4; ++q) {
            if (haveNext) stage_half(0, q >> 1, q & 1, 2 * i + 2);
            bf16x8 af[2][2];
            if (q == 0) {
                if (haveNext) asm volatile("s_waitcnt vmcnt(2)" ::: "memory");
                else          asm volatile("s_waitcnt vmcnt(0)" ::: "memory");
                __builtin_amdgcn_s_barrier();
#pragma unroll
                for (int n = 0; n < 4; ++n)
#pragma unroll
                    for (int ks = 0; ks < 2; ++ks) bfr[n][ks] = rdB(1, n, ks);
#pragma unroll
                for (int mm = 0; mm < 2; ++mm)
#pragma unroll
                    for (int ks = 0; ks < 2; ++ks) af[mm][ks] = rdA(1, q * 2 + mm, ks);
            } else {
#pragma unroll
                for (int mm = 0; mm < 2; ++mm)
#pragma unroll
                    for (int ks = 0; ks < 2; ++ks) af[mm][ks] = rdA(1, q * 2 + mm, ks);
                __builtin_amdgcn_s_barrier();
            }
            __builtin_amdgcn_s_setprio(1);
#pragma unroll
            for (int mm = 0; mm < 2; ++mm)
#pragma unroll
                for (int n = 0; n < 4; ++n)
#pragma unroll
                    for (int ks = 0; ks < 2; ++ks)
                        acc[q * 2 + mm][n] = __builtin_amdgcn_mfma_f32_16x16x32_bf16(
                            af[mm][ks], bfr[n][ks], acc[q * 2 + mm][n], 0, 0, 0);
            __builtin_amdgcn_s_setprio(0);
            __builtin_amdgcn_s_barrier();
        }
    }

    // epilogue: C/D layout col = lane&15, row = (lane>>4)*4 + j
#pragma unroll
    for (int m = 0; m < 8; ++m) {
        const long orow_base = r0 + wr + m * 16 + fh * 4;
#pragma unroll
        for (int n = 0; n < 4; ++n) {
            const long ocol = c0 + wc + n * 16 + fr;
#pragma unroll
            for (int j = 0; j < 4; ++j) {
                const long orow = orow_base + j;
                float vv = acc[m][n][j];
                if (EPI == 0) {
                    ((unsigned short*)Cout)[orow * NCOLS + ocol] = f2bf_rne(vv);
                } else {
                    vv += bias[ocol];
                    vv = vv > 0.f ? vv : 0.f;
                    ((float*)Cout)[orow * NCOLS + ocol] = vv;
                }
            }
        }
    }
}

// ---------------- depthwise dilated conv + BN stats, v6 ----------------
// R4's proven sliding-window (v2) with ONE change: per-block partial sums are
// stored (coalesced float4) to a scratch array instead of 2.88M atomicAdds on
// 256 cache lines of sums[2][H]. part1[idx][h], part2[idx][h], idx = b>>1.
__global__ __launch_bounds__(256) void conv_bn_v6(
    const unsigned short* __restrict__ p,   // [MROWS][H] bf16
    const float* __restrict__ w,            // [12][H]
    float* __restrict__ ph_f32,             // [MROWS][H] fp32 out
    unsigned short* __restrict__ ph_b,      // [MROWS][H] bf16 out
    float* __restrict__ part)               // [2][NPART][H]
{
    const int tid   = threadIdx.x;
    const int b     = blockIdx.x;
    const int half  = b & 1;
    const int idx   = b >> 1;               // 0..NPART-1
    const int chunk = idx % SCHUNKS;
    const int np    = idx / SCHUNKS;
    const int par   = np & 1;
    const int n     = np >> 1;
    const int h0    = half * 1024 + tid * 4;

    float wk[12][4];
#pragma unroll
    for (int k = 0; k < 12; ++k) {
        float4 v = *(const float4*)&w[k * H_DIM + h0];
        wk[k][0] = v.x; wk[k][1] = v.y; wk[k][2] = v.z; wk[k][3] = v.w;
    }

    const long b0 = ((long)n * T_DIM + par) * (long)H_DIM + h0;
    const int s0 = chunk * TCHUNK;

    float win[12][4];
#pragma unroll
    for (int j = 0; j < 12; ++j) {
        const int s = s0 + j - 10;
        if (s >= 0 && s < S_LEN) {
            ushort4 v = *(const ushort4*)&p[b0 + (long)s * (2 * H_DIM)];
            win[j][0] = bf2f(v.x); win[j][1] = bf2f(v.y);
            win[j][2] = bf2f(v.z); win[j][3] = bf2f(v.w);
        } else {
            win[j][0] = 0.f; win[j][1] = 0.f; win[j][2] = 0.f; win[j][3] = 0.f;
        }
    }

    float st1[4] = {0.f, 0.f, 0.f, 0.f};
    float st2[4] = {0.f, 0.f, 0.f, 0.f};

    for (int ss = 0; ss < TCHUNK; ss += 12) {
#pragma unroll
        for (int uu = 0; uu < 12; ++uu) {
            const int s = s0 + ss + uu;
            if (s < S_LEN) {
                float out[4];
#pragma unroll
                for (int c = 0; c < 4; ++c) out[c] = win[(uu + 10) % 12][c];
#pragma unroll
                for (int k = 0; k < 12; ++k)
#pragma unroll
                    for (int c = 0; c < 4; ++c)
                        out[c] += wk[k][c] * win[(uu + k) % 12][c];

                const long base = b0 + (long)s * (2 * H_DIM);
                *(float4*)&ph_f32[base] = make_float4(out[0], out[1], out[2], out[3]);
                ushort4 ob;
                ob.x = f2bf_rne(out[0]); ob.y = f2bf_rne(out[1]);
                ob.z = f2bf_rne(out[2]); ob.w = f2bf_rne(out[3]);
                *(ushort4*)&ph_b[base] = ob;
#pragma unroll
                for (int c = 0; c < 4; ++c) { st1[c] += out[c]; st2[c] += out[c] * out[c]; }
            }
            {
                const int sn = s0 + ss + uu + 2;
                if (sn < S_LEN) {
                    ushort4 v = *(const ushort4*)&p[b0 + (long)sn * (2 * H_DIM)];
                    win[uu][0] = bf2f(v.x); win[uu][1] = bf2f(v.y);
                    win[uu][2] = bf2f(v.z); win[uu][3] = bf2f(v.w);
                } else {
                    win[uu][0] = 0.f; win[uu][1] = 0.f; win[uu][2] = 0.f; win[uu][3] = 0.f;
                }
            }
        }
    }

    // coalesced partial stores: no atomics
    *(float4*)&part[(long)idx * H_DIM + h0] = make_float4(st1[0], st1[1], st1[2], st1[3]);
    *(float4*)&part[((long)NPART + idx) * H_DIM + h0] = make_float4(st2[0], st2[1], st2[2], st2[3]);
}

// ---------------- reduce partials + BN finalize --------------------------
// s = gamma*rsqrt(var+eps); shift = beta - mean*s. Grid: H/256 blocks.
__global__ __launch_bounds__(256) void bn_reduce_finalize(
    const float* __restrict__ part,         // [2][NPART][H]
    const float* __restrict__ gamma,
    const float* __restrict__ beta,
    float* __restrict__ sshift) {
    const int h = blockIdx.x * 256 + threadIdx.x;
    float s1 = 0.f, s2 = 0.f;
    for (int i = 0; i < NPART; ++i) {
        s1 += part[(long)i * H_DIM + h];
        s2 += part[((long)NPART + i) * H_DIM + h];
    }
    float mean = s1 * (1.f / (float)MROWS);
    float var  = s2 * (1.f / (float)MROWS) - mean * mean;
    float s = gamma[h] * rsqrtf(var + BN_EPS);
    sshift[h] = s;
    sshift[H_DIM + h] = beta[h] - mean * s;
}

// wu2[o,h] = bf16(wu[o,h] * s[h])
__global__ void scale_wu(const float* __restrict__ wu,
                         const float* __restrict__ sshift,
                         unsigned short* __restrict__ wu2) {
    int idx = blockIdx.x * blockDim.x + threadIdx.x;
    int stride = gridDim.x * blockDim.x;
    for (; idx < O_DIM * H_DIM; idx += stride) {
        int h = idx & (H_DIM - 1);
        wu2[idx] = f2bf_rne(wu[idx] * sshift[h]);
    }
}

// bias2[o] = bu[o] + sum_h shift[h]*wu[o,h]
__global__ __launch_bounds__(256) void bias2_kernel(
    const float* __restrict__ wu,
    const float* __restrict__ sshift,
    const float* __restrict__ bu,
    float* __restrict__ bias2) {
    const int o = blockIdx.x;
    float part = 0.f;
    for (int h = threadIdx.x; h < H_DIM; h += 256)
        part += sshift[H_DIM + h] * wu[(long)o * H_DIM + h];
#pragma unroll
    for (int off = 32; off > 0; off >>= 1) part += __shfl_down(part, off, 64);
    __shared__ float red[4];
    const int wv = threadIdx.x >> 6, lane = threadIdx.x & 63;
    if (lane == 0) red[wv] = part;
    __syncthreads();
    if (threadIdx.x == 0) bias2[o] = bu[o] + red[0] + red[1] + red[2] + red[3];
}

extern "C" void kernel_launch(void* const* d_in, const int* in_sizes, int n_in,
                              void* d_out, int out_size, void* d_ws, size_t ws_size,
                              hipStream_t stream) {
    const float* inputs = (const float*)d_in[0];   // [T,N,I]
    const float* wv     = (const float*)d_in[1];   // [H,I]
    const float* gamma  = (const float*)d_in[2];   // [H]
    const float* beta   = (const float*)d_in[3];   // [H]
    const float* wu     = (const float*)d_in[4];   // [O,H]
    const float* bu     = (const float*)d_in[5];   // [O]
    const float* mw     = (const float*)d_in[6];   // [K,H]

    float* out_h  = (float*)d_out;                           // [N,T,O] = 33.5M floats
    float* out_ph = out_h + (size_t)MROWS * O_DIM;           // [N,T,H] = 67M floats

    // p (bf16) parked in d_out's h-region: exactly MROWS*H*2 = 134,217,728 B
    unsigned short* p_b = (unsigned short*)d_out;

    char* ws = (char*)d_ws;
    unsigned short* ph_b  = (unsigned short*)ws;                     // 134,217,728 B
    unsigned short* in_b  = (unsigned short*)(ws + 134217728);       //  67,108,864 B
    unsigned short* wv_b  = (unsigned short*)(ws + 201326592);       //   4,194,304 B
    unsigned short* wu2_b = (unsigned short*)(ws + 205520896);       //   4,194,304 B
    float* sshift = (float*)(ws + 209731584);                        //      16,384 B
    float* bias2  = (float*)(ws + 209747968);                        //       4,096 B
    // conv partials (2*NPART*H*4 = 11,534,336 B) overlay in_b's region,
    // which is dead after GEMM1 completes.
    float* part   = (float*)(ws + 134217728);

    // 1. convert inputs / wv to bf16
    cvt_kernel<<<2048, 256, 0, stream>>>(inputs, in_b, (T_DIM * N_DIM * I_DIM) / 4);
    cvt_kernel<<<512, 256, 0, stream>>>(wv, wv_b, (H_DIM * I_DIM) / 4);

    // 2. GEMM1: p[n*T+t, h] = sum_i inputs[t,n,i]*wv[h,i] -> bf16 in d_out h-region
    gemm256<1, 0, I_DIM, H_DIM><<<(MROWS / 256) * (H_DIM / 256), 512, 0, stream>>>(
        in_b, wv_b, (void*)p_b, nullptr);

    // 3. conv + p_hatt (fp32 out + bf16 copy) + per-block BN partials (no atomics)
    conv_bn_v6<<<2 * NPART, 256, 0, stream>>>(p_b, mw, out_ph, ph_b, part);

    // 4. reduce partials + BN finalize + fold into GEMM2 weights/bias
    bn_reduce_finalize<<<H_DIM / 256, 256, 0, stream>>>(part, gamma, beta, sshift);
    scale_wu<<<2048, 256, 0, stream>>>(wu, sshift, wu2_b);
    bias2_kernel<<<O_DIM, 256, 0, stream>>>(wu, sshift, bu, bias2);

    // 5. GEMM2: h = relu(ph_b @ wu2^T + bias2) -> out_h
    gemm256<0, 1, H_DIM, O_DIM><<<(MROWS / 256) * (O_DIM / 256), 512, 0, stream>>>(
        ph_b, wu2_b, (void*)out_h, bias2);
}

// Round 10
// 474.534 us; speedup vs baseline: 1.1025x; 1.1025x over previous
//
#include <hip/hip_runtime.h>
#include <hip/hip_bf16.h>
#include <stdint.h>

// Problem constants (from setup_inputs)
#define T_DIM 2048
#define N_DIM 16
#define I_DIM 1024
#define H_DIM 2048
#define O_DIM 1024
#define K_TAPS 12
#define MROWS (N_DIM * T_DIM)   // 32768 rows of (n,t)
#define BN_EPS 1e-5f

// conv decomposition: subsample space per parity, length 1024
#define S_LEN 1024
#define TCHUNK 48
#define SCHUNKS 22              // ceil(1024/48)

typedef __attribute__((ext_vector_type(8))) short bf16x8;
typedef __attribute__((ext_vector_type(4))) float f32x4;

__device__ __forceinline__ unsigned short f2bf_rne(float f) {
    union { float f; unsigned u; } v; v.f = f;
    unsigned u = v.u;
    unsigned r = u + 0x7fffu + ((u >> 16) & 1u);
    return (unsigned short)(r >> 16);
}

__device__ __forceinline__ float bf2f(unsigned short x) {
    union { unsigned u; float f; } v; v.u = ((unsigned)x) << 16; return v.f;
}

__device__ __forceinline__ bf16x8 pack8(const float4& a, const float4& b) {
    bf16x8 v;
    v[0] = (short)f2bf_rne(a.x); v[1] = (short)f2bf_rne(a.y);
    v[2] = (short)f2bf_rne(a.z); v[3] = (short)f2bf_rne(a.w);
    v[4] = (short)f2bf_rne(b.x); v[5] = (short)f2bf_rne(b.y);
    v[6] = (short)f2bf_rne(b.z); v[7] = (short)f2bf_rne(b.w);
    return v;
}

// ---------------- fp32 -> bf16 conversion (vectorized x4) ----------------
__global__ void cvt_kernel(const float* __restrict__ in, unsigned short* __restrict__ out, int n4) {
    int i = blockIdx.x * blockDim.x + threadIdx.x;
    int stride = gridDim.x * blockDim.x;
    for (; i < n4; i += stride) {
        float4 v = ((const float4*)in)[i];
        ushort4 o;
        o.x = f2bf_rne(v.x); o.y = f2bf_rne(v.y);
        o.z = f2bf_rne(v.z); o.w = f2bf_rne(v.w);
        ((ushort4*)out)[i] = o;
    }
}

__device__ __forceinline__ void gload_lds16(const void* g, void* l) {
    __builtin_amdgcn_global_load_lds(
        (const __attribute__((address_space(1))) unsigned int*)g,
        (__attribute__((address_space(3))) unsigned int*)l, 16, 0, 0);
}

// ------- 256x256 8-phase GEMM, A = fp32 (reg-staged, converts in-staging) ----
// R5-verified variant, used for GEMM1 only (inputs fp32 are L3-resident so the
// x8 panel re-read is absorbed; eliminates the 402 MB cvt pass).
template<int PERM, int EPI, int KD, int NCOLS>
__global__ __launch_bounds__(512, 2) void gemm256_a32(
    const float* __restrict__ A,
    const unsigned short* __restrict__ B,
    void* __restrict__ Cout,
    const float* __restrict__ bias)
{
    __shared__ char lds[131072];   // buf b: A at b*65536, B at b*65536+32768

    const int tid  = threadIdx.x;
    const int wid  = tid >> 6;
    const int lane = tid & 63;
    const int wr   = (wid >> 2) * 128;
    const int wc   = (wid & 3) * 64;
    const int fr   = lane & 15;
    const int fh   = lane >> 4;

    const int nwg = gridDim.x;
    const int lin = blockIdx.x;
    const int tile = (lin & 7) * (nwg >> 3) + (lin >> 3);
    const int ntx = NCOLS / 256;
    const long c0 = (long)(tile % ntx) * 256;
    const long r0 = (long)(tile / ntx) * 256;

    long aBase, aStride;
    if (PERM) {
        const long n0 = r0 / T_DIM;
        const long t0 = r0 % T_DIM;
        aBase = (t0 * N_DIM + n0) * (long)KD;
        aStride = (long)N_DIM * KD;
    } else {
        aBase = r0 * (long)KD;
        aStride = KD;
    }
    const long bBase = c0 * (long)KD;

    auto stageB = [&](int buf, int si, int kt) {
        const int row = si * 64 + (tid >> 3);
        const int g   = (tid & 7) ^ (row & 7);
        const long gelem = bBase + (long)row * (long)KD + (long)kt * 64 + g * 8;
        gload_lds16((const char*)B + gelem * 2,
                    lds + buf * 65536 + 32768 + si * 8192 + tid * 16);
    };
    auto loadA = [&](float4* dst, int wi, int kt) {
        const int row = wi * 64 + (tid >> 3);
        const long base = aBase + (long)row * aStride + (long)kt * 64 + (tid & 7) * 8;
        dst[0] = *(const float4*)(A + base);
        dst[1] = *(const float4*)(A + base + 4);
    };
    auto writeA = [&](int buf, int wi, const float4* src) {
        const int row = wi * 64 + (tid >> 3);
        const int blk = tid & 7;
        *(bf16x8*)(lds + buf * 65536 + row * 128 + (((blk ^ (row & 7))) << 4)) =
            pack8(src[0], src[1]);
    };
    auto rdA = [&](int buf, int m, int ks) -> bf16x8 {
        const int row = wr + m * 16 + fr;
        const int blk = ks * 4 + fh;
        return *(const bf16x8*)(lds + buf * 65536 + row * 128 + ((blk ^ (row & 7)) << 4));
    };
    auto rdB = [&](int buf, int n, int ks) -> bf16x8 {
        const int row = wc + n * 16 + fr;
        const int blk = ks * 4 + fh;
        return *(const bf16x8*)(lds + buf * 65536 + 32768 + row * 128 + ((blk ^ (row & 7)) << 4));
    };

    f32x4 acc[8][4] = {};
    float4 aA[8], aB[8];

    // prologue: stage tile 0 into buf0; preload A(tile 1) into aB
    stageB(0, 0, 0); stageB(0, 1, 0); stageB(0, 2, 0); stageB(0, 3, 0);
    loadA(&aA[0], 0, 0); loadA(&aA[2], 1, 0); loadA(&aA[4], 2, 0); loadA(&aA[6], 3, 0);
    writeA(0, 0, &aA[0]); writeA(0, 1, &aA[2]); writeA(0, 2, &aA[4]); writeA(0, 3, &aA[6]);
    loadA(&aB[0], 0, 1); loadA(&aB[2], 1, 1); loadA(&aB[4], 2, 1); loadA(&aB[6], 3, 1);
    asm volatile("s_waitcnt vmcnt(8) lgkmcnt(0)" ::: "memory");
    __builtin_amdgcn_s_barrier();

    const int KT  = KD / 64;
    const int KT2 = KT / 2;
    for (int i = 0; i < KT2; ++i) {
        const bool haveNext = (i + 1 < KT2);
        const int tB1 = 2 * i + 1, tN = 2 * i + 2, tNN = 2 * i + 3;

        {
            bf16x8 bfr[4][2];
#pragma unroll
            for (int q = 0; q < 4; ++q) {
                writeA(1, q, &aB[2 * q]);
                if (q == 0) { stageB(1, 0, tB1); stageB(1, 1, tB1); stageB(1, 2, tB1); stageB(1, 3, tB1); }
                if (haveNext) loadA(&aA[2 * q], q, tN);
                if (q == 0) {
#pragma unroll
                    for (int n = 0; n < 4; ++n)
#pragma unroll
                        for (int ks = 0; ks < 2; ++ks) bfr[n][ks] = rdB(0, n, ks);
                }
                bf16x8 af[2][2];
#pragma unroll
                for (int mm = 0; mm < 2; ++mm)
#pragma unroll
                    for (int ks = 0; ks < 2; ++ks) af[mm][ks] = rdA(0, q * 2 + mm, ks);
                __builtin_amdgcn_s_setprio(1);
#pragma unroll
                for (int mm = 0; mm < 2; ++mm)
#pragma unroll
                    for (int n = 0; n < 4; ++n)
#pragma unroll
                        for (int ks = 0; ks < 2; ++ks)
                            acc[q * 2 + mm][n] = __builtin_amdgcn_mfma_f32_16x16x32_bf16(
                                af[mm][ks], bfr[n][ks], acc[q * 2 + mm][n], 0, 0, 0);
                __builtin_amdgcn_s_setprio(0);
                if (q == 3) {
                    if (haveNext) asm volatile("s_waitcnt vmcnt(8) lgkmcnt(0)" ::: "memory");
                    else          asm volatile("s_waitcnt vmcnt(0) lgkmcnt(0)" ::: "memory");
                }
                __builtin_amdgcn_s_barrier();
            }
        }

        {
            bf16x8 bfr[4][2];
#pragma unroll
            for (int q = 0; q < 4; ++q) {
                if (haveNext) {
                    writeA(0, q, &aA[2 * q]);
                    if (q == 0) { stageB(0, 0, tN); stageB(0, 1, tN); stageB(0, 2, tN); stageB(0, 3, tN); }
                    loadA(&aB[2 * q], q, tNN);
                }
                if (q == 0) {
#pragma unroll
                    for (int n = 0; n < 4; ++n)
#pragma unroll
                        for (int ks = 0; ks < 2; ++ks) bfr[n][ks] = rdB(1, n, ks);
                }
                bf16x8 af[2][2];
#pragma unroll
                for (int mm = 0; mm < 2; ++mm)
#pragma unroll
                    for (int ks = 0; ks < 2; ++ks) af[mm][ks] = rdA(1, q * 2 + mm, ks);
                __builtin_amdgcn_s_setprio(1);
#pragma unroll
                for (int mm = 0; mm < 2; ++mm)
#pragma unroll
                    for (int n = 0; n < 4; ++n)
#pragma unroll
                        for (int ks = 0; ks < 2; ++ks)
                            acc[q * 2 + mm][n] = __builtin_amdgcn_mfma_f32_16x16x32_bf16(
                                af[mm][ks], bfr[n][ks], acc[q * 2 + mm][n], 0, 0, 0);
                __builtin_amdgcn_s_setprio(0);
                if (q == 3) {
                    if (haveNext) asm volatile("s_waitcnt vmcnt(8) lgkmcnt(0)" ::: "memory");
                    else          asm volatile("s_waitcnt vmcnt(0) lgkmcnt(0)" ::: "memory");
                }
                __builtin_amdgcn_s_barrier();
            }
        }
    }

#pragma unroll
    for (int m = 0; m < 8; ++m) {
        const long orow_base = r0 + wr + m * 16 + fh * 4;
#pragma unroll
        for (int n = 0; n < 4; ++n) {
            const long ocol = c0 + wc + n * 16 + fr;
#pragma unroll
            for (int j = 0; j < 4; ++j) {
                const long orow = orow_base + j;
                float vv = acc[m][n][j];
                if (EPI == 0) {
                    ((unsigned short*)Cout)[orow * NCOLS + ocol] = f2bf_rne(vv);
                } else {
                    vv += bias[ocol];
                    vv = vv > 0.f ? vv : 0.f;
                    ((float*)Cout)[orow * NCOLS + ocol] = vv;
                }
            }
        }
    }
}

// ---------------- 256x256 8-phase bf16 MFMA GEMM, C = A * B^T ----------------
// (R4-verified version: gload_lds both paths, counted vmcnt(2) at phases 0/4.)
template<int PERM, int EPI, int KD, int NCOLS>
__global__ __launch_bounds__(512, 2) void gemm256(
    const unsigned short* __restrict__ A,
    const unsigned short* __restrict__ B,
    void* __restrict__ Cout,
    const float* __restrict__ bias)
{
    __shared__ char lds[131072];

    const int tid  = threadIdx.x;
    const int wid  = tid >> 6;
    const int lane = tid & 63;
    const int wr   = (wid >> 2) * 128;
    const int wc   = (wid & 3) * 64;
    const int fr   = lane & 15;
    const int fh   = lane >> 4;

    const int nwg = gridDim.x;
    const int lin = blockIdx.x;
    const int tile = (lin & 7) * (nwg >> 3) + (lin >> 3);
    const int ntx = NCOLS / 256;
    const long c0 = (long)(tile % ntx) * 256;
    const long r0 = (long)(tile / ntx) * 256;

    long aBase, aStride;
    if (PERM) {
        const long n0 = r0 / T_DIM;
        const long t0 = r0 % T_DIM;
        aBase = (t0 * N_DIM + n0) * (long)KD;
        aStride = (long)N_DIM * KD;
    } else {
        aBase = r0 * (long)KD;
        aStride = KD;
    }
    const long bBase = c0 * (long)KD;

    auto stage_half = [&](int buf, int mat, int h, int kt) {
        char* mbase = lds + buf * 65536 + mat * 32768 + h * 16384;
#pragma unroll
        for (int j = 0; j < 2; ++j) {
            const int row = h * 128 + j * 64 + (tid >> 3);
            const int g   = (tid & 7) ^ (row & 7);
            long gelem;
            if (mat == 0) gelem = aBase + (long)row * aStride + (long)kt * 64 + g * 8;
            else          gelem = bBase + (long)row * (long)KD + (long)kt * 64 + g * 8;
            gload_lds16((const char*)(mat == 0 ? A : B) + gelem * 2,
                        mbase + j * 8192 + tid * 16);
        }
    };

    auto rdA = [&](int buf, int m, int ks) -> bf16x8 {
        const int row = wr + m * 16 + fr;
        const int blk = ks * 4 + fh;
        return *(const bf16x8*)(lds + buf * 65536 + row * 128 + ((blk ^ (row & 7)) << 4));
    };
    auto rdB = [&](int buf, int n, int ks) -> bf16x8 {
        const int row = wc + n * 16 + fr;
        const int blk = ks * 4 + fh;
        return *(const bf16x8*)(lds + buf * 65536 + 32768 + row * 128 + ((blk ^ (row & 7)) << 4));
    };

    f32x4 acc[8][4] = {};

    stage_half(0, 0, 0, 0); stage_half(0, 0, 1, 0);
    stage_half(0, 1, 0, 0); stage_half(0, 1, 1, 0);

    const int KT  = KD / 64;
    const int KT2 = KT / 2;
    for (int i = 0; i < KT2; ++i) {
        const int tB = 2 * i + 1;
        const bool haveNext = (i + 1 < KT2);
        bf16x8 bfr[4][2];

#pragma unroll
        for (int q = 0; q < 4; ++q) {
            stage_half(1, q >> 1, q & 1, tB);
            bf16x8 af[2][2];
            if (q == 0) {
                asm volatile("s_waitcnt vmcnt(2)" ::: "memory");
                __builtin_amdgcn_s_barrier();
#pragma unroll
                for (int n = 0; n < 4; ++n)
#pragma unroll
                    for (int ks = 0; ks < 2; ++ks) bfr[n][ks] = rdB(0, n, ks);
#pragma unroll
                for (int mm = 0; mm < 2; ++mm)
#pragma unroll
                    for (int ks = 0; ks < 2; ++ks) af[mm][ks] = rdA(0, q * 2 + mm, ks);
            } else {
#pragma unroll
                for (int mm = 0; mm < 2; ++mm)
#pragma unroll
                    for (int ks = 0; ks < 2; ++ks) af[mm][ks] = rdA(0, q * 2 + mm, ks);
                __builtin_amdgcn_s_barrier();
            }
            __builtin_amdgcn_s_setprio(1);
#pragma unroll
            for (int mm = 0; mm < 2; ++mm)
#pragma unroll
                for (int n = 0; n < 4; ++n)
#pragma unroll
                    for (int ks = 0; ks < 2; ++ks)
                        acc[q * 2 + mm][n] = __builtin_amdgcn_mfma_f32_16x16x32_bf16(
                            af[mm][ks], bfr[n][ks], acc[q * 2 + mm][n], 0, 0, 0);
            __builtin_amdgcn_s_setprio(0);
            __builtin_amdgcn_s_barrier();
        }

#pragma unroll
        for (int q = 0; q < 4; ++q) {
            if (haveNext) stage_half(0, q >> 1, q & 1, 2 * i + 2);
            bf16x8 af[2][2];
            if (q == 0) {
                if (haveNext) asm volatile("s_waitcnt vmcnt(2)" ::: "memory");
                else          asm volatile("s_waitcnt vmcnt(0)" ::: "memory");
                __builtin_amdgcn_s_barrier();
#pragma unroll
                for (int n = 0; n < 4; ++n)
#pragma unroll
                    for (int ks = 0; ks < 2; ++ks) bfr[n][ks] = rdB(1, n, ks);
#pragma unroll
                for (int mm = 0; mm < 2; ++mm)
#pragma unroll
                    for (int ks = 0; ks < 2; ++ks) af[mm][ks] = rdA(1, q * 2 + mm, ks);
            } else {
#pragma unroll
                for (int mm = 0; mm < 2; ++mm)
#pragma unroll
                    for (int ks = 0; ks < 2; ++ks) af[mm][ks] = rdA(1, q * 2 + mm, ks);
                __builtin_amdgcn_s_barrier();
            }
            __builtin_amdgcn_s_setprio(1);
#pragma unroll
            for (int mm = 0; mm < 2; ++mm)
#pragma unroll
                for (int n = 0; n < 4; ++n)
#pragma unroll
                    for (int ks = 0; ks < 2; ++ks)
                        acc[q * 2 + mm][n] = __builtin_amdgcn_mfma_f32_16x16x32_bf16(
                            af[mm][ks], bfr[n][ks], acc[q * 2 + mm][n], 0, 0, 0);
            __builtin_amdgcn_s_setprio(0);
            __builtin_amdgcn_s_barrier();
        }
    }

#pragma unroll
    for (int m = 0; m < 8; ++m) {
        const long orow_base = r0 + wr + m * 16 + fh * 4;
#pragma unroll
        for (int n = 0; n < 4; ++n) {
            const long ocol = c0 + wc + n * 16 + fr;
#pragma unroll
            for (int j = 0; j < 4; ++j) {
                const long orow = orow_base + j;
                float vv = acc[m][n][j];
                if (EPI == 0) {
                    ((unsigned short*)Cout)[orow * NCOLS + ocol] = f2bf_rne(vv);
                } else {
                    vv += bias[ocol];
                    vv = vv > 0.f ? vv : 0.f;
                    ((float*)Cout)[orow * NCOLS + ocol] = vv;
                }
            }
        }
    }
}

// ---------------- depthwise dilated conv + BN stats, v2 (R4-verified) -------
__global__ __launch_bounds__(256) void conv_bn_v2(
    const unsigned short* __restrict__ p,   // [MROWS][H] bf16
    const float* __restrict__ w,            // [12][H]
    float* __restrict__ ph_f32,             // [MROWS][H] fp32 out
    unsigned short* __restrict__ ph_b,      // [MROWS][H] bf16 out
    float* __restrict__ sums)               // [2][H] zeroed
{
    const int tid   = threadIdx.x;
    const int b     = blockIdx.x;
    const int half  = b & 1;
    const int chunk = (b >> 1) % SCHUNKS;
    const int np    = (b >> 1) / SCHUNKS;
    const int par   = np & 1;
    const int n     = np >> 1;
    const int h0    = half * 1024 + tid * 4;

    float wk[12][4];
#pragma unroll
    for (int k = 0; k < 12; ++k) {
        float4 v = *(const float4*)&w[k * H_DIM + h0];
        wk[k][0] = v.x; wk[k][1] = v.y; wk[k][2] = v.z; wk[k][3] = v.w;
    }

    const long b0 = ((long)n * T_DIM + par) * (long)H_DIM + h0;
    const int s0 = chunk * TCHUNK;

    float win[12][4];
#pragma unroll
    for (int j = 0; j < 12; ++j) {
        const int s = s0 + j - 10;
        if (s >= 0 && s < S_LEN) {
            ushort4 v = *(const ushort4*)&p[b0 + (long)s * (2 * H_DIM)];
            win[j][0] = bf2f(v.x); win[j][1] = bf2f(v.y);
            win[j][2] = bf2f(v.z); win[j][3] = bf2f(v.w);
        } else {
            win[j][0] = 0.f; win[j][1] = 0.f; win[j][2] = 0.f; win[j][3] = 0.f;
        }
    }

    float st1[4] = {0.f, 0.f, 0.f, 0.f};
    float st2[4] = {0.f, 0.f, 0.f, 0.f};

    for (int ss = 0; ss < TCHUNK; ss += 12) {
#pragma unroll
        for (int uu = 0; uu < 12; ++uu) {
            const int s = s0 + ss + uu;
            if (s < S_LEN) {
                float out[4];
#pragma unroll
                for (int c = 0; c < 4; ++c) out[c] = win[(uu + 10) % 12][c];
#pragma unroll
                for (int k = 0; k < 12; ++k)
#pragma unroll
                    for (int c = 0; c < 4; ++c)
                        out[c] += wk[k][c] * win[(uu + k) % 12][c];

                const long base = b0 + (long)s * (2 * H_DIM);
                *(float4*)&ph_f32[base] = make_float4(out[0], out[1], out[2], out[3]);
                ushort4 ob;
                ob.x = f2bf_rne(out[0]); ob.y = f2bf_rne(out[1]);
                ob.z = f2bf_rne(out[2]); ob.w = f2bf_rne(out[3]);
                *(ushort4*)&ph_b[base] = ob;
#pragma unroll
                for (int c = 0; c < 4; ++c) { st1[c] += out[c]; st2[c] += out[c] * out[c]; }
            }
            {
                const int sn = s0 + ss + uu + 2;
                if (sn < S_LEN) {
                    ushort4 v = *(const ushort4*)&p[b0 + (long)sn * (2 * H_DIM)];
                    win[uu][0] = bf2f(v.x); win[uu][1] = bf2f(v.y);
                    win[uu][2] = bf2f(v.z); win[uu][3] = bf2f(v.w);
                } else {
                    win[uu][0] = 0.f; win[uu][1] = 0.f; win[uu][2] = 0.f; win[uu][3] = 0.f;
                }
            }
        }
    }

#pragma unroll
    for (int c = 0; c < 4; ++c) {
        atomicAdd(&sums[h0 + c], st1[c]);
        atomicAdd(&sums[H_DIM + h0 + c], st2[c]);
    }
}

// ---------------- BN finalize: s = gamma*rsqrt(var+eps); shift = beta - mean*s ----
__global__ void bn_finalize(const float* __restrict__ sums,
                            const float* __restrict__ gamma,
                            const float* __restrict__ beta,
                            float* __restrict__ sshift) {
    int h = blockIdx.x * blockDim.x + threadIdx.x;
    if (h >= H_DIM) return;
    float mean = sums[h] * (1.f / (float)MROWS);
    float var  = sums[H_DIM + h] * (1.f / (float)MROWS) - mean * mean;
    float s = gamma[h] * rsqrtf(var + BN_EPS);
    sshift[h] = s;
    sshift[H_DIM + h] = beta[h] - mean * s;
}

// wu2[o,h] = bf16(wu[o,h] * s[h])
__global__ void scale_wu(const float* __restrict__ wu,
                         const float* __restrict__ sshift,
                         unsigned short* __restrict__ wu2) {
    int idx = blockIdx.x * blockDim.x + threadIdx.x;
    int stride = gridDim.x * blockDim.x;
    for (; idx < O_DIM * H_DIM; idx += stride) {
        int h = idx & (H_DIM - 1);
        wu2[idx] = f2bf_rne(wu[idx] * sshift[h]);
    }
}

// bias2[o] = bu[o] + sum_h shift[h]*wu[o,h]
__global__ __launch_bounds__(256) void bias2_kernel(
    const float* __restrict__ wu,
    const float* __restrict__ sshift,
    const float* __restrict__ bu,
    float* __restrict__ bias2) {
    const int o = blockIdx.x;
    float part = 0.f;
    for (int h = threadIdx.x; h < H_DIM; h += 256)
        part += sshift[H_DIM + h] * wu[(long)o * H_DIM + h];
#pragma unroll
    for (int off = 32; off > 0; off >>= 1) part += __shfl_down(part, off, 64);
    __shared__ float red[4];
    const int wv = threadIdx.x >> 6, lane = threadIdx.x & 63;
    if (lane == 0) red[wv] = part;
    __syncthreads();
    if (threadIdx.x == 0) bias2[o] = bu[o] + red[0] + red[1] + red[2] + red[3];
}

extern "C" void kernel_launch(void* const* d_in, const int* in_sizes, int n_in,
                              void* d_out, int out_size, void* d_ws, size_t ws_size,
                              hipStream_t stream) {
    const float* inputs = (const float*)d_in[0];   // [T,N,I]
    const float* wv     = (const float*)d_in[1];   // [H,I]
    const float* gamma  = (const float*)d_in[2];   // [H]
    const float* beta   = (const float*)d_in[3];   // [H]
    const float* wu     = (const float*)d_in[4];   // [O,H]
    const float* bu     = (const float*)d_in[5];   // [O]
    const float* mw     = (const float*)d_in[6];   // [K,H]

    float* out_h  = (float*)d_out;                           // [N,T,O] = 33.5M floats
    float* out_ph = out_h + (size_t)MROWS * O_DIM;           // [N,T,H] = 67M floats

    // p (bf16) parked in d_out's h-region: exactly MROWS*H*2 = 134,217,728 B
    unsigned short* p_b = (unsigned short*)d_out;

    char* ws = (char*)d_ws;
    unsigned short* ph_b  = (unsigned short*)ws;                     // 134,217,728 B
    unsigned short* wv_b  = (unsigned short*)(ws + 201326592);       //   4,194,304 B
    unsigned short* wu2_b = (unsigned short*)(ws + 205520896);       //   4,194,304 B
    float* sums   = (float*)(ws + 209715200);                        //      16,384 B
    float* sshift = (float*)(ws + 209731584);                        //      16,384 B
    float* bias2  = (float*)(ws + 209747968);                        //       4,096 B

    hipMemsetAsync(sums, 0, 2 * H_DIM * sizeof(float), stream);

    // 1. convert wv to bf16 (inputs stay fp32 — GEMM1 converts in-staging)
    cvt_kernel<<<512, 256, 0, stream>>>(wv, wv_b, (H_DIM * I_DIM) / 4);

    // 2. GEMM1 (fp32 A): p[n*T+t, h] = sum_i inputs[t,n,i]*wv[h,i] -> bf16 in d_out
    gemm256_a32<1, 0, I_DIM, H_DIM><<<(MROWS / 256) * (H_DIM / 256), 512, 0, stream>>>(
        inputs, wv_b, (void*)p_b, nullptr);

    // 3. conv + p_hatt (fp32 out + bf16 copy) + BN partial sums
    conv_bn_v2<<<2 * SCHUNKS * 2 * N_DIM, 256, 0, stream>>>(p_b, mw, out_ph, ph_b, sums);

    // 4. BN finalize + fold into GEMM2 weights/bias
    bn_finalize<<<(H_DIM + 255) / 256, 256, 0, stream>>>(sums, gamma, beta, sshift);
    scale_wu<<<2048, 256, 0, stream>>>(wu, sshift, wu2_b);
    bias2_kernel<<<O_DIM, 256, 0, stream>>>(wu, sshift, bu, bias2);

    // 5. GEMM2: h = relu(ph_b @ wu2^T + bias2) -> out_h
    gemm256<0, 1, H_DIM, O_DIM><<<(MROWS / 256) * (O_DIM / 256), 512, 0, stream>>>(
        ph_b, wu2_b, (void*)out_h, bias2);
}

// Round 12
// 468.573 us; speedup vs baseline: 1.1165x; 1.0127x over previous
//
#include <hip/hip_runtime.h>
#include <hip/hip_bf16.h>
#include <stdint.h>

// Problem constants (from setup_inputs)
#define T_DIM 2048
#define N_DIM 16
#define I_DIM 1024
#define H_DIM 2048
#define O_DIM 1024
#define K_TAPS 12
#define MROWS (N_DIM * T_DIM)   // 32768 rows of (n,t)
#define BN_EPS 1e-5f

// conv decomposition: subsample space per parity, length 1024
#define S_LEN 1024
#define TCHUNK 48
#define SCHUNKS 22              // ceil(1024/48)

typedef __attribute__((ext_vector_type(8))) short bf16x8;
typedef __attribute__((ext_vector_type(4))) float f32x4;

__device__ __forceinline__ unsigned short f2bf_rne(float f) {
    union { float f; unsigned u; } v; v.f = f;
    unsigned u = v.u;
    unsigned r = u + 0x7fffu + ((u >> 16) & 1u);
    return (unsigned short)(r >> 16);
}

__device__ __forceinline__ float bf2f(unsigned short x) {
    union { unsigned u; float f; } v; v.u = ((unsigned)x) << 16; return v.f;
}

// ---------------- fp32 -> bf16 conversion (vectorized x4) ----------------
__global__ void cvt_kernel(const float* __restrict__ in, unsigned short* __restrict__ out, int n4) {
    int i = blockIdx.x * blockDim.x + threadIdx.x;
    int stride = gridDim.x * blockDim.x;
    for (; i < n4; i += stride) {
        float4 v = ((const float4*)in)[i];
        ushort4 o;
        o.x = f2bf_rne(v.x); o.y = f2bf_rne(v.y);
        o.z = f2bf_rne(v.z); o.w = f2bf_rne(v.w);
        ((ushort4*)out)[i] = o;
    }
}

__device__ __forceinline__ void gload_lds16(const void* g, void* l) {
    __builtin_amdgcn_global_load_lds(
        (const __attribute__((address_space(1))) unsigned int*)g,
        (__attribute__((address_space(3))) unsigned int*)l, 16, 0, 0);
}

// ---------------- 256x256 8-phase bf16 MFMA GEMM, C = A * B^T ----------------
// (R4-verified version: gload_lds both paths, counted vmcnt(2) at phases 0/4.)
// EPI=1 epilogue uses non-temporal stores (out_h is write-once, never re-read).
template<int PERM, int EPI, int KD, int NCOLS>
__global__ __launch_bounds__(512, 2) void gemm256(
    const unsigned short* __restrict__ A,
    const unsigned short* __restrict__ B,
    void* __restrict__ Cout,
    const float* __restrict__ bias)
{
    __shared__ char lds[131072];   // buf b: A at b*65536, B at b*65536+32768

    const int tid  = threadIdx.x;
    const int wid  = tid >> 6;
    const int lane = tid & 63;
    const int wr   = (wid >> 2) * 128;    // wave row offset (2 warps_m)
    const int wc   = (wid & 3) * 64;      // wave col offset (4 warps_n)
    const int fr   = lane & 15;
    const int fh   = lane >> 4;           // 0..3

    // XCD-aware bijective swizzle (nwg % 8 == 0 for both launches)
    const int nwg = gridDim.x;
    const int lin = blockIdx.x;
    const int tile = (lin & 7) * (nwg >> 3) + (lin >> 3);
    const int ntx = NCOLS / 256;
    const long c0 = (long)(tile % ntx) * 256;
    const long r0 = (long)(tile / ntx) * 256;

    long aBase, aStride;
    if (PERM) {
        const long n0 = r0 / T_DIM;
        const long t0 = r0 % T_DIM;       // 256-row tile stays within one n
        aBase = (t0 * N_DIM + n0) * (long)KD;
        aStride = (long)N_DIM * KD;
    } else {
        aBase = r0 * (long)KD;
        aStride = KD;
    }
    const long bBase = c0 * (long)KD;

    auto stage_half = [&](int buf, int mat, int h, int kt) {
        char* mbase = lds + buf * 65536 + mat * 32768 + h * 16384;
#pragma unroll
        for (int j = 0; j < 2; ++j) {
            const int row = h * 128 + j * 64 + (tid >> 3);
            const int g   = (tid & 7) ^ (row & 7);      // inverse swizzle on source
            long gelem;
            if (mat == 0) gelem = aBase + (long)row * aStride + (long)kt * 64 + g * 8;
            else          gelem = bBase + (long)row * (long)KD + (long)kt * 64 + g * 8;
            gload_lds16((const char*)(mat == 0 ? A : B) + gelem * 2,
                        mbase + j * 8192 + tid * 16);
        }
    };

    auto rdA = [&](int buf, int m, int ks) -> bf16x8 {
        const int row = wr + m * 16 + fr;
        const int blk = ks * 4 + fh;
        return *(const bf16x8*)(lds + buf * 65536 + row * 128 + ((blk ^ (row & 7)) << 4));
    };
    auto rdB = [&](int buf, int n, int ks) -> bf16x8 {
        const int row = wc + n * 16 + fr;
        const int blk = ks * 4 + fh;
        return *(const bf16x8*)(lds + buf * 65536 + 32768 + row * 128 + ((blk ^ (row & 7)) << 4));
    };

    f32x4 acc[8][4] = {};

    // prologue: stage tile 0 into buf0 (8 loads/thread)
    stage_half(0, 0, 0, 0); stage_half(0, 0, 1, 0);
    stage_half(0, 1, 0, 0); stage_half(0, 1, 1, 0);

    const int KT  = KD / 64;
    const int KT2 = KT / 2;
    for (int i = 0; i < KT2; ++i) {
        const int tB = 2 * i + 1;
        const bool haveNext = (i + 1 < KT2);
        bf16x8 bfr[4][2];

        // ---- phases 0-3: compute tile 2i from buf0; stage tile 2i+1 into buf1
#pragma unroll
        for (int q = 0; q < 4; ++q) {
            stage_half(1, q >> 1, q & 1, tB);
            bf16x8 af[2][2];
            if (q == 0) {
                asm volatile("s_waitcnt vmcnt(2)" ::: "memory");
                __builtin_amdgcn_s_barrier();
#pragma unroll
                for (int n = 0; n < 4; ++n)
#pragma unroll
                    for (int ks = 0; ks < 2; ++ks) bfr[n][ks] = rdB(0, n, ks);
#pragma unroll
                for (int mm = 0; mm < 2; ++mm)
#pragma unroll
                    for (int ks = 0; ks < 2; ++ks) af[mm][ks] = rdA(0, q * 2 + mm, ks);
            } else {
#pragma unroll
                for (int mm = 0; mm < 2; ++mm)
#pragma unroll
                    for (int ks = 0; ks < 2; ++ks) af[mm][ks] = rdA(0, q * 2 + mm, ks);
                __builtin_amdgcn_s_barrier();
            }
            __builtin_amdgcn_s_setprio(1);
#pragma unroll
            for (int mm = 0; mm < 2; ++mm)
#pragma unroll
                for (int n = 0; n < 4; ++n)
#pragma unroll
                    for (int ks = 0; ks < 2; ++ks)
                        acc[q * 2 + mm][n] = __builtin_amdgcn_mfma_f32_16x16x32_bf16(
                            af[mm][ks], bfr[n][ks], acc[q * 2 + mm][n], 0, 0, 0);
            __builtin_amdgcn_s_setprio(0);
            __builtin_amdgcn_s_barrier();
        }

        // ---- phases 4-7: compute tile 2i+1 from buf1; stage tile 2i+2 into buf0
#pragma unroll
        for (int q = 0; q < 4; ++q) {
            if (haveNext) stage_half(0, q >> 1, q & 1, 2 * i + 2);
            bf16x8 af[2][2];
            if (q == 0) {
                if (haveNext) asm volatile("s_waitcnt vmcnt(2)" ::: "memory");
                else          asm volatile("s_waitcnt vmcnt(0)" ::: "memory");
                __builtin_amdgcn_s_barrier();
#pragma unroll
                for (int n = 0; n < 4; ++n)
#pragma unroll
                    for (int ks = 0; ks < 2; ++ks) bfr[n][ks] = rdB(1, n, ks);
#pragma unroll
                for (int mm = 0; mm < 2; ++mm)
#pragma unroll
                    for (int ks = 0; ks < 2; ++ks) af[mm][ks] = rdA(1, q * 2 + mm, ks);
            } else {
#pragma unroll
                for (int mm = 0; mm < 2; ++mm)
#pragma unroll
                    for (int ks = 0; ks < 2; ++ks) af[mm][ks] = rdA(1, q * 2 + mm, ks);
                __builtin_amdgcn_s_barrier();
            }
            __builtin_amdgcn_s_setprio(1);
#pragma unroll
            for (int mm = 0; mm < 2; ++mm)
#pragma unroll
                for (int n = 0; n < 4; ++n)
#pragma unroll
                    for (int ks = 0; ks < 2; ++ks)
                        acc[q * 2 + mm][n] = __builtin_amdgcn_mfma_f32_16x16x32_bf16(
                            af[mm][ks], bfr[n][ks], acc[q * 2 + mm][n], 0, 0, 0);
            __builtin_amdgcn_s_setprio(0);
            __builtin_amdgcn_s_barrier();
        }
    }

    // epilogue: C/D layout col = lane&15, row = (lane>>4)*4 + j
#pragma unroll
    for (int m = 0; m < 8; ++m) {
        const long orow_base = r0 + wr + m * 16 + fh * 4;
#pragma unroll
        for (int n = 0; n < 4; ++n) {
            const long ocol = c0 + wc + n * 16 + fr;
#pragma unroll
            for (int j = 0; j < 4; ++j) {
                const long orow = orow_base + j;
                float vv = acc[m][n][j];
                if (EPI == 0) {
                    ((unsigned short*)Cout)[orow * NCOLS + ocol] = f2bf_rne(vv);
                } else {
                    vv += bias[ocol];
                    vv = vv > 0.f ? vv : 0.f;
                    __builtin_nontemporal_store(vv, &((float*)Cout)[orow * NCOLS + ocol]);
                }
            }
        }
    }
}

// ---------------- depthwise dilated conv + BN stats, v2 (R4-verified) -------
// One tweak vs R4: ph_f32 stores are non-temporal (write-once stream, never
// re-read) so L2/L3 keep p (being read) and ph_b (GEMM2's x4-reread operand).
// nt store uses the clang ext_vector f32x4 (HIP float4 is a class -> rejected).
__global__ __launch_bounds__(256) void conv_bn_v2(
    const unsigned short* __restrict__ p,   // [MROWS][H] bf16
    const float* __restrict__ w,            // [12][H]
    float* __restrict__ ph_f32,             // [MROWS][H] fp32 out
    unsigned short* __restrict__ ph_b,      // [MROWS][H] bf16 out
    float* __restrict__ sums)               // [2][H] zeroed
{
    const int tid   = threadIdx.x;
    const int b     = blockIdx.x;
    const int half  = b & 1;
    const int chunk = (b >> 1) % SCHUNKS;
    const int np    = (b >> 1) / SCHUNKS;
    const int par   = np & 1;
    const int n     = np >> 1;
    const int h0    = half * 1024 + tid * 4;

    float wk[12][4];
#pragma unroll
    for (int k = 0; k < 12; ++k) {
        float4 v = *(const float4*)&w[k * H_DIM + h0];
        wk[k][0] = v.x; wk[k][1] = v.y; wk[k][2] = v.z; wk[k][3] = v.w;
    }

    const long b0 = ((long)n * T_DIM + par) * (long)H_DIM + h0;
    const int s0 = chunk * TCHUNK;

    float win[12][4];
#pragma unroll
    for (int j = 0; j < 12; ++j) {
        const int s = s0 + j - 10;
        if (s >= 0 && s < S_LEN) {
            ushort4 v = *(const ushort4*)&p[b0 + (long)s * (2 * H_DIM)];
            win[j][0] = bf2f(v.x); win[j][1] = bf2f(v.y);
            win[j][2] = bf2f(v.z); win[j][3] = bf2f(v.w);
        } else {
            win[j][0] = 0.f; win[j][1] = 0.f; win[j][2] = 0.f; win[j][3] = 0.f;
        }
    }

    float st1[4] = {0.f, 0.f, 0.f, 0.f};
    float st2[4] = {0.f, 0.f, 0.f, 0.f};

    for (int ss = 0; ss < TCHUNK; ss += 12) {
#pragma unroll
        for (int uu = 0; uu < 12; ++uu) {
            const int s = s0 + ss + uu;
            if (s < S_LEN) {
                float out[4];
#pragma unroll
                for (int c = 0; c < 4; ++c) out[c] = win[(uu + 10) % 12][c];
#pragma unroll
                for (int k = 0; k < 12; ++k)
#pragma unroll
                    for (int c = 0; c < 4; ++c)
                        out[c] += wk[k][c] * win[(uu + k) % 12][c];

                const long base = b0 + (long)s * (2 * H_DIM);
                f32x4 ov;
                ov[0] = out[0]; ov[1] = out[1]; ov[2] = out[2]; ov[3] = out[3];
                __builtin_nontemporal_store(ov, (f32x4*)&ph_f32[base]);
                ushort4 ob;
                ob.x = f2bf_rne(out[0]); ob.y = f2bf_rne(out[1]);
                ob.z = f2bf_rne(out[2]); ob.w = f2bf_rne(out[3]);
                *(ushort4*)&ph_b[base] = ob;
#pragma unroll
                for (int c = 0; c < 4; ++c) { st1[c] += out[c]; st2[c] += out[c] * out[c]; }
            }
            {
                const int sn = s0 + ss + uu + 2;
                if (sn < S_LEN) {
                    ushort4 v = *(const ushort4*)&p[b0 + (long)sn * (2 * H_DIM)];
                    win[uu][0] = bf2f(v.x); win[uu][1] = bf2f(v.y);
                    win[uu][2] = bf2f(v.z); win[uu][3] = bf2f(v.w);
                } else {
                    win[uu][0] = 0.f; win[uu][1] = 0.f; win[uu][2] = 0.f; win[uu][3] = 0.f;
                }
            }
        }
    }

#pragma unroll
    for (int c = 0; c < 4; ++c) {
        atomicAdd(&sums[h0 + c], st1[c]);
        atomicAdd(&sums[H_DIM + h0 + c], st2[c]);
    }
}

// ---------------- BN finalize: s = gamma*rsqrt(var+eps); shift = beta - mean*s ----
__global__ void bn_finalize(const float* __restrict__ sums,
                            const float* __restrict__ gamma,
                            const float* __restrict__ beta,
                            float* __restrict__ sshift) {
    int h = blockIdx.x * blockDim.x + threadIdx.x;
    if (h >= H_DIM) return;
    float mean = sums[h] * (1.f / (float)MROWS);
    float var  = sums[H_DIM + h] * (1.f / (float)MROWS) - mean * mean;
    float s = gamma[h] * rsqrtf(var + BN_EPS);
    sshift[h] = s;
    sshift[H_DIM + h] = beta[h] - mean * s;
}

// wu2[o,h] = bf16(wu[o,h] * s[h])
__global__ void scale_wu(const float* __restrict__ wu,
                         const float* __restrict__ sshift,
                         unsigned short* __restrict__ wu2) {
    int idx = blockIdx.x * blockDim.x + threadIdx.x;
    int stride = gridDim.x * blockDim.x;
    for (; idx < O_DIM * H_DIM; idx += stride) {
        int h = idx & (H_DIM - 1);
        wu2[idx] = f2bf_rne(wu[idx] * sshift[h]);
    }
}

// bias2[o] = bu[o] + sum_h shift[h]*wu[o,h]
__global__ __launch_bounds__(256) void bias2_kernel(
    const float* __restrict__ wu,
    const float* __restrict__ sshift,
    const float* __restrict__ bu,
    float* __restrict__ bias2) {
    const int o = blockIdx.x;
    float part = 0.f;
    for (int h = threadIdx.x; h < H_DIM; h += 256)
        part += sshift[H_DIM + h] * wu[(long)o * H_DIM + h];
#pragma unroll
    for (int off = 32; off > 0; off >>= 1) part += __shfl_down(part, off, 64);
    __shared__ float red[4];
    const int wv = threadIdx.x >> 6, lane = threadIdx.x & 63;
    if (lane == 0) red[wv] = part;
    __syncthreads();
    if (threadIdx.x == 0) bias2[o] = bu[o] + red[0] + red[1] + red[2] + red[3];
}

extern "C" void kernel_launch(void* const* d_in, const int* in_sizes, int n_in,
                              void* d_out, int out_size, void* d_ws, size_t ws_size,
                              hipStream_t stream) {
    const float* inputs = (const float*)d_in[0];   // [T,N,I]
    const float* wv     = (const float*)d_in[1];   // [H,I]
    const float* gamma  = (const float*)d_in[2];   // [H]
    const float* beta   = (const float*)d_in[3];   // [H]
    const float* wu     = (const float*)d_in[4];   // [O,H]
    const float* bu     = (const float*)d_in[5];   // [O]
    const float* mw     = (const float*)d_in[6];   // [K,H]

    float* out_h  = (float*)d_out;                           // [N,T,O] = 33.5M floats
    float* out_ph = out_h + (size_t)MROWS * O_DIM;           // [N,T,H] = 67M floats

    // p (bf16) parked in d_out's h-region: exactly MROWS*H*2 = 134,217,728 B
    unsigned short* p_b = (unsigned short*)d_out;

    char* ws = (char*)d_ws;
    unsigned short* ph_b  = (unsigned short*)ws;                     // 134,217,728 B
    unsigned short* in_b  = (unsigned short*)(ws + 134217728);       //  67,108,864 B
    unsigned short* wv_b  = (unsigned short*)(ws + 201326592);       //   4,194,304 B
    unsigned short* wu2_b = (unsigned short*)(ws + 205520896);       //   4,194,304 B
    float* sums   = (float*)(ws + 209715200);                        //      16,384 B
    float* sshift = (float*)(ws + 209731584);                        //      16,384 B
    float* bias2  = (float*)(ws + 209747968);                        //       4,096 B

    hipMemsetAsync(sums, 0, 2 * H_DIM * sizeof(float), stream);

    // 1. convert inputs / wv to bf16
    cvt_kernel<<<2048, 256, 0, stream>>>(inputs, in_b, (T_DIM * N_DIM * I_DIM) / 4);
    cvt_kernel<<<512, 256, 0, stream>>>(wv, wv_b, (H_DIM * I_DIM) / 4);

    // 2. GEMM1: p[n*T+t, h] = sum_i inputs[t,n,i]*wv[h,i] -> bf16 in d_out h-region
    gemm256<1, 0, I_DIM, H_DIM><<<(MROWS / 256) * (H_DIM / 256), 512, 0, stream>>>(
        in_b, wv_b, (void*)p_b, nullptr);

    // 3. conv + p_hatt (fp32 nt-out + bf16 copy) + BN partial sums
    conv_bn_v2<<<2 * SCHUNKS * 2 * N_DIM, 256, 0, stream>>>(p_b, mw, out_ph, ph_b, sums);

    // 4. BN finalize + fold into GEMM2 weights/bias
    bn_finalize<<<(H_DIM + 255) / 256, 256, 0, stream>>>(sums, gamma, beta, sshift);
    scale_wu<<<2048, 256, 0, stream>>>(wu, sshift, wu2_b);
    bias2_kernel<<<O_DIM, 256, 0, stream>>>(wu, sshift, bu, bias2);

    // 5. GEMM2: h = relu(ph_b @ wu2^T + bias2) -> out_h
    gemm256<0, 1, H_DIM, O_DIM><<<(MROWS / 256) * (O_DIM / 256), 512, 0, stream>>>(
        ph_b, wu2_b, (void*)out_h, bias2);
}